// Round 7
// baseline (15.278 us; speedup 1.0000x reference)
//
#include <hip/hip_runtime.h>
#include <stdint.h>

#define NB   16      // NUM_BATCHES
#define K    32      // MAX_NUM_NEIGHBORS
#define R2   0.0625f // RADIUS^2 = 0.25^2, exact in f32
#define WPB  4       // waves (targets) per block
#define MAXC 256     // per-wave candidate buffer (observed max ~60; >=6 sigma)

// Single fused kernel: ONE WAVE per target. NO cross-wave communication:
//   bounds: every lane binary-searches lower_bound(batch, min(lane,NB)) in
//           parallel (13 uniform trips); s,e picked via two __shfl's.
//           No LDS, no block barrier.
//   scan  : wave-uniform trip count, software-pipelined (prefetch next point
//           while compacting current). sq[j] recomputed inline from x[j] with
//           the exact numpy expression (contract off) -> bit-identical.
//           Passing keys compacted into per-wave LDS via ballot + popcount.
//   rank  : lane p ranks key p against all cnt keys (broadcast LDS reads);
//           rank < K -> scatter src index into res[rank].
//   sync  : buf/res are per-wave only -> s_waitcnt lgkmcnt(0) (wave-local
//           LDS drain) replaces both __syncthreads().
//   Key = (ordered d2 bits << 32) | j  ->  uint64 ascending == (d2 asc, j asc)
//   == lax.top_k stable tie-break. FP path identical to the passing kernel.
__global__ __launch_bounds__(256) void radius_knn_fused(
    const float* __restrict__ x,
    const int* __restrict__ batch,
    int n,
    int* __restrict__ out,
    int row_stride /* = n*K */) {
#pragma clang fp contract(off)
    __shared__ uint64_t buf[WPB][MAXC];
    __shared__ int      res[WPB][K];

    const int tid  = threadIdx.x;
    const int lane = tid & 63;
    const int wid  = tid >> 6;
    const int i    = blockIdx.x * WPB + wid;   // n % WPB == 0: no early return

    const int b = batch[i];

    // ---- per-wave bounds: 64 parallel binary searches (lanes >16 redundant) ----
    const int tgt = lane < NB ? lane : NB;     // lower_bound(batch, tgt)
    int lo = 0, hi = n;
    while (lo < hi) {
        int mid = (lo + hi) >> 1;
        if (batch[mid] < tgt) lo = mid + 1; else hi = mid;
    }
    const int s = __shfl(lo, b, 64);           // b is wave-uniform
    const int e = __shfl(lo, b + 1, 64);

    // ---- target point + its squared norm (numpy-exact: no contraction) ----
    const float xi0 = x[i * 3 + 0];
    const float xi1 = x[i * 3 + 1];
    const float xi2 = x[i * 3 + 2];
    const float q0 = xi0 * xi0, q1 = xi1 * xi1, q2 = xi2 * xi2;
    const float sqi = (q0 + q1) + q2;

    // ---- scan + ballot-compaction, software-pipelined ----
    const int range = e - s;
    const int iters = (range + 63) >> 6;
    int cbase = 0;

    int j  = s + lane;
    int jc = (j < e) ? j : s;                  // clamp for safe loads
    float y0 = x[jc * 3 + 0];
    float y1 = x[jc * 3 + 1];
    float y2 = x[jc * 3 + 2];

    for (int it = 0; it < iters; ++it) {
        // prefetch next iteration's point (clamped address is always valid)
        const int jn  = j + 64;
        const int jnc = (jn < e) ? jn : s;
        const float z0 = x[jnc * 3 + 0];
        const float z1 = x[jnc * 3 + 1];
        const float z2 = x[jnc * 3 + 2];

        // sq[j] inline, identical expression to numpy's elementwise square+sum
        float p0 = y0 * y0, p1 = y1 * y1, p2 = y2 * y2;
        float sqj = (p0 + p1) + p2;
        // sgemm-style K=3 dot: fma chain accumulating from 0.
        float dot = xi0 * y0;
        dot = fmaf(xi1, y1, dot);
        dot = fmaf(xi2, y2, dot);
        float d2 = (sqi + sqj) - 2.0f * dot;
        bool pass = (j < e) && (j != i) && (d2 <= R2);

        d2 = d2 + 0.0f;                        // normalize -0.0 -> +0.0
        uint32_t u = __float_as_uint(d2);
        u = (u & 0x80000000u) ? ~u : (u | 0x80000000u);
        uint64_t key = ((uint64_t)u << 32) | (uint32_t)jc;

        uint64_t mask = __ballot(pass);
        if (pass) {
            int off = cbase + __popcll(mask & ((1ull << lane) - 1ull));
            if (off < MAXC) buf[wid][off] = key;
        }
        cbase += (int)__popcll(mask);

        j = jn; jc = jnc; y0 = z0; y1 = z1; y2 = z2;
    }
    int cnt = cbase < MAXC ? cbase : MAXC;
    const int nsel = cnt < K ? cnt : K;

    // wave-local LDS drain: buf[wid] is written/read by THIS wave only.
    __asm__ volatile("s_waitcnt lgkmcnt(0)" ::: "memory");

    // ---- rank + scatter: lane p ranks key p against all cnt keys ----
    for (int p = lane; p < cnt; p += 64) {
        uint64_t kp = buf[wid][p];
        int r = 0;
        for (int q = 0; q < cnt; ++q)
            r += (buf[wid][q] < kp) ? 1 : 0;
        if (r < K) res[wid][r] = (int)(uint32_t)(kp & 0xffffffffu);
    }

    // wave-local LDS drain: res[wid] is written/read by THIS wave only.
    __asm__ volatile("s_waitcnt lgkmcnt(0)" ::: "memory");

    // ---- epilogue: row 0 = src (lanes 0..31), row 1 = tgt (lanes 32..63) ----
    const long base = (long)i * K;
    if (lane < K) {
        out[base + lane] = (lane < nsel) ? res[wid][lane] : -1;
    } else {
        const int l2 = lane - K;
        out[row_stride + base + l2] = (l2 < nsel) ? i : -1;
    }
}

extern "C" void kernel_launch(void* const* d_in, const int* in_sizes, int n_in,
                              void* d_out, int out_size, void* d_ws, size_t ws_size,
                              hipStream_t stream) {
    const float* x     = (const float*)d_in[0];
    const int*   batch = (const int*)d_in[1];
    const int    n     = in_sizes[1];          // 8192
    int*         out   = (int*)d_out;
    const int row_stride = out_size / 2;       // n*K

    const int blocks = n / WPB;                // one wave per target
    radius_knn_fused<<<blocks, 256, 0, stream>>>(x, batch, n, out, row_stride);
}

// Round 8
// 14.290 us; speedup vs baseline: 1.0691x; 1.0691x over previous
//
#include <hip/hip_runtime.h>
#include <stdint.h>

#define NB   16      // NUM_BATCHES
#define K    32      // MAX_NUM_NEIGHBORS
#define R2   0.0625f // RADIUS^2 = 0.25^2, exact in f32
#define WPB  4       // waves (targets) per block
#define MAXC 256     // per-wave candidate buffer (observed max ~60; >=6 sigma)

// Single fused kernel: ONE WAVE per target.  [best-measured config: 14.28 us]
//   bounds: threads 0..NB of each block binary-search lower_bound(batch, tid)
//           in PARALLEL -> sstart[NB+1] in LDS (one 13-load latency chain per
//           block instead of two per wave).
//   scan  : wave-uniform trip count, software-pipelined (prefetch next point
//           while compacting current). sq[j] recomputed inline from x[j] with
//           the exact numpy expression (contract off) -> bit-identical.
//           Passing keys compacted into per-wave LDS via ballot + popcount.
//   rank  : lane p ranks key p against all cnt keys (broadcast LDS reads);
//           rank < K -> scatter src index into res[rank].
//   Key = (ordered d2 bits << 32) | j  ->  uint64 ascending == (d2 asc, j asc)
//   == lax.top_k stable tie-break. FP path identical to the passing kernel.
__global__ __launch_bounds__(256) void radius_knn_fused(
    const float* __restrict__ x,
    const int* __restrict__ batch,
    int n,
    int* __restrict__ out,
    int row_stride /* = n*K */) {
#pragma clang fp contract(off)
    __shared__ uint64_t buf[WPB][MAXC];
    __shared__ int      res[WPB][K];
    __shared__ int      sstart[NB + 1];

    const int tid  = threadIdx.x;
    const int lane = tid & 63;
    const int wid  = tid >> 6;
    const int i    = blockIdx.x * WPB + wid;   // n % WPB == 0: no early return

    // ---- cooperative batch bounds: 17 parallel binary searches ----
    if (tid <= NB) {
        const int target = tid;                // lower_bound(batch, target)
        int lo = 0, hi = n;
        while (lo < hi) {
            int mid = (lo + hi) >> 1;
            if (batch[mid] < target) lo = mid + 1; else hi = mid;
        }
        sstart[tid] = lo;
    }
    __syncthreads();

    const int b = batch[i];
    const int s = sstart[b];
    const int e = sstart[b + 1];

    // ---- target point + its squared norm (numpy-exact: no contraction) ----
    const float xi0 = x[i * 3 + 0];
    const float xi1 = x[i * 3 + 1];
    const float xi2 = x[i * 3 + 2];
    const float q0 = xi0 * xi0, q1 = xi1 * xi1, q2 = xi2 * xi2;
    const float sqi = (q0 + q1) + q2;

    // ---- scan + ballot-compaction, software-pipelined ----
    const int range = e - s;
    const int iters = (range + 63) >> 6;
    int cbase = 0;

    int j  = s + lane;
    int jc = (j < e) ? j : s;                  // clamp for safe loads
    float y0 = x[jc * 3 + 0];
    float y1 = x[jc * 3 + 1];
    float y2 = x[jc * 3 + 2];

    for (int it = 0; it < iters; ++it) {
        // prefetch next iteration's point (clamped address is always valid)
        const int jn  = j + 64;
        const int jnc = (jn < e) ? jn : s;
        const float z0 = x[jnc * 3 + 0];
        const float z1 = x[jnc * 3 + 1];
        const float z2 = x[jnc * 3 + 2];

        // sq[j] inline, identical expression to numpy's elementwise square+sum
        float p0 = y0 * y0, p1 = y1 * y1, p2 = y2 * y2;
        float sqj = (p0 + p1) + p2;
        // sgemm-style K=3 dot: fma chain accumulating from 0.
        float dot = xi0 * y0;
        dot = fmaf(xi1, y1, dot);
        dot = fmaf(xi2, y2, dot);
        float d2 = (sqi + sqj) - 2.0f * dot;
        bool pass = (j < e) && (j != i) && (d2 <= R2);

        d2 = d2 + 0.0f;                        // normalize -0.0 -> +0.0
        uint32_t u = __float_as_uint(d2);
        u = (u & 0x80000000u) ? ~u : (u | 0x80000000u);
        uint64_t key = ((uint64_t)u << 32) | (uint32_t)jc;

        uint64_t mask = __ballot(pass);
        if (pass) {
            int off = cbase + __popcll(mask & ((1ull << lane) - 1ull));
            if (off < MAXC) buf[wid][off] = key;
        }
        cbase += (int)__popcll(mask);

        j = jn; jc = jnc; y0 = z0; y1 = z1; y2 = z2;
    }
    int cnt = cbase < MAXC ? cbase : MAXC;
    const int nsel = cnt < K ? cnt : K;

    __syncthreads();   // buf visible (uniform: every thread reaches)

    // ---- rank + scatter: lane p ranks key p against all cnt keys ----
    for (int p = lane; p < cnt; p += 64) {
        uint64_t kp = buf[wid][p];
        int r = 0;
        for (int q = 0; q < cnt; ++q)
            r += (buf[wid][q] < kp) ? 1 : 0;
        if (r < K) res[wid][r] = (int)(uint32_t)(kp & 0xffffffffu);
    }

    __syncthreads();   // res visible (uniform)

    // ---- epilogue: row 0 = src (lanes 0..31), row 1 = tgt (lanes 32..63) ----
    const long base = (long)i * K;
    if (lane < K) {
        out[base + lane] = (lane < nsel) ? res[wid][lane] : -1;
    } else {
        const int l2 = lane - K;
        out[row_stride + base + l2] = (l2 < nsel) ? i : -1;
    }
}

extern "C" void kernel_launch(void* const* d_in, const int* in_sizes, int n_in,
                              void* d_out, int out_size, void* d_ws, size_t ws_size,
                              hipStream_t stream) {
    const float* x     = (const float*)d_in[0];
    const int*   batch = (const int*)d_in[1];
    const int    n     = in_sizes[1];          // 8192
    int*         out   = (int*)d_out;
    const int row_stride = out_size / 2;       // n*K

    const int blocks = n / WPB;                // one wave per target
    radius_knn_fused<<<blocks, 256, 0, stream>>>(x, batch, n, out, row_stride);
}